// Round 6
// baseline (21.985 us; speedup 1.0000x reference)
//
#include <hip/hip_runtime.h>

// Problem constants (match reference setup_inputs)
#define BATCH   32
#define NCLS    80
#define MAXB    50
#define NANCH   12288                    // 3*64*64 anchors per image
#define BLK     256
#define APT     2                        // anchors per thread
#define BLKS_PER_IMG (NANCH / (BLK * APT))  // 24
#define ROWLEN  85                       // NCLS + 5
#define SUM_SCALE 16384.0f               // 2^14 fixed-point scale for packed sum

typedef unsigned long long u64;

// Packed per-image accumulator (one u64 per image, zeroed by memset node):
//   [63:58] arrival count (<= 24)
//   [57:44] positive count (<= 12288)
//   [43:0]  sum * 2^14, round-to-nearest (max ~7.5e10 << 2^44)
// Single-location integer atomicAdd: commutative (bit-exact deterministic),
// totally ordered (the 24th arriver's old+own == exact final) -> no fences,
// no second kernel.
__global__ __launch_bounds__(BLK) void yolo_fused(
    const float* __restrict__ pred,      // (B, NANCH, 85)
    const float* __restrict__ ann,       // (B, MAXB, 5)
    const float* __restrict__ anchors,   // (NANCH, 4)
    u64*         __restrict__ gpack,     // (BATCH), zeroed each launch
    float*       __restrict__ out)       // (2, B)
{
    const int blk = blockIdx.x;                       // 0..23
    const int b   = blockIdx.y;                       // image
    const int n0  = blk * (BLK * APT) + threadIdx.x;  // anchor 0; anchor 1 = n0+BLK

    // Order-preserving compaction of valid annotations (cls != -1).
    // Loss-equivalent to the reference's iou=-1 masking (argmax only consumed
    // when positive, which requires a valid overlapping box; empty -> loss 0).
    __shared__ float4 s_box[MAXB];   // x1,y1,x2,y2
    __shared__ float  s_area[MAXB];
    __shared__ float  s_cls[MAXB];
    __shared__ int    s_nv;

    if (threadIdx.x < 64) {
        const int lane = threadIdx.x;
        float cx = 0, cy = 0, w = 0, h = 0, cl = -1.0f;
        if (lane < MAXB) {
            const float* a = ann + ((size_t)b * MAXB + lane) * 5;
            cx = a[0]; cy = a[1]; w = a[2]; h = a[3]; cl = a[4];
        }
        const bool valid = (lane < MAXB) && (cl != -1.0f);
        const u64 mask = __ballot(valid);
        if (valid) {
            const int cidx = __popcll(mask & ((1ull << lane) - 1ull));
            const float x1 = cx - w * 0.5f, y1 = cy - h * 0.5f;
            const float x2 = cx + w * 0.5f, y2 = cy + h * 0.5f;
            s_box[cidx]  = make_float4(x1, y1, x2, y2);
            s_area[cidx] = (x2 - x1) * (y2 - y1);
            s_cls[cidx]  = cl;
        }
        if (lane == 0) s_nv = __popcll(mask);
    }
    __syncthreads();

    // Two anchors per thread share each iteration's LDS annotation read.
    const float4 A0 = *reinterpret_cast<const float4*>(anchors + (size_t)n0 * 4);
    const float4 A1 = *reinterpret_cast<const float4*>(anchors + (size_t)(n0 + BLK) * 4);
    const float ax1_0 = A0.x - A0.z * 0.5f, ay1_0 = A0.y - A0.w * 0.5f;
    const float ax2_0 = A0.x + A0.z * 0.5f, ay2_0 = A0.y + A0.w * 0.5f;
    const float ax1_1 = A1.x - A1.z * 0.5f, ay1_1 = A1.y - A1.w * 0.5f;
    const float ax2_1 = A1.x + A1.z * 0.5f, ay2_1 = A1.y + A1.w * 0.5f;
    const float area0 = (ax2_0 - ax1_0) * (ay2_0 - ay1_0);
    const float area1 = (ax2_1 - ax1_1) * (ay2_1 - ay1_1);

    const int nv = s_nv;
    float best0 = 0.0f, best1 = 0.0f;    // all IoUs >= 0
    int   bm0 = 0, bm1 = 0;
    #pragma unroll 2
    for (int m = 0; m < nv; ++m) {
        const float4 bb = s_box[m];      // LDS broadcast, shared by both anchors
        const float ab  = s_area[m];
        float iw0 = fminf(ax2_0, bb.z) - fmaxf(ax1_0, bb.x); iw0 = fmaxf(iw0, 0.0f);
        float ih0 = fminf(ay2_0, bb.w) - fmaxf(ay1_0, bb.y); ih0 = fmaxf(ih0, 0.0f);
        float iw1 = fminf(ax2_1, bb.z) - fmaxf(ax1_1, bb.x); iw1 = fmaxf(iw1, 0.0f);
        float ih1 = fminf(ay2_1, bb.w) - fmaxf(ay1_1, bb.y); ih1 = fmaxf(ih1, 0.0f);
        const float in0 = iw0 * ih0;
        const float in1 = iw1 * ih1;
        const float iou0 = in0 * __builtin_amdgcn_rcpf(area0 + ab - in0); // union >= 256
        const float iou1 = in1 * __builtin_amdgcn_rcpf(area1 + ab - in1);
        // strict > keeps first occurrence, matching jnp.argmax
        if (iou0 > best0) { best0 = iou0; bm0 = m; }
        if (iou1 > best1) { best1 = iou1; bm1 = m; }
    }

    const bool pos0 = (best0 >= 0.5f);
    const bool pos1 = (best1 >= 0.5f);
    float local = 0.0f;

    // BCE vs one-hot: -log(p[ac]) + log(1-p[ac]) - sum_c log(1-p[c])
    // sum of logs -> 5 chunked log-of-products ((1-p) >= .01: no underflow)
    if (pos0) {
        const int ac = (int)fminf(fmaxf(s_cls[bm0], 0.0f), (float)(NCLS - 1));
        const float* prow = pred + ((size_t)b * NANCH + n0) * ROWLEN + 5;
        float S = 0.0f;
        #pragma unroll
        for (int ch = 0; ch < 5; ++ch) {
            float prod = 1.0f;
            #pragma unroll
            for (int j = 0; j < 16; ++j)
                prod = __builtin_fmaf(-prow[ch * 16 + j], prod, prod);
            S += __logf(prod);
        }
        const float pa = prow[ac];
        local += -__logf(pa) + __logf(1.0f - pa) - S;
    }
    if (pos1) {
        const int ac = (int)fminf(fmaxf(s_cls[bm1], 0.0f), (float)(NCLS - 1));
        const float* prow = pred + ((size_t)b * NANCH + n0 + BLK) * ROWLEN + 5;
        float S = 0.0f;
        #pragma unroll
        for (int ch = 0; ch < 5; ++ch) {
            float prod = 1.0f;
            #pragma unroll
            for (int j = 0; j < 16; ++j)
                prod = __builtin_fmaf(-prow[ch * 16 + j], prod, prod);
            S += __logf(prod);
        }
        const float pa = prow[ac];
        local += -__logf(pa) + __logf(1.0f - pa) - S;
    }

    // Deterministic block reduction: wave shuffle then cross-wave via LDS
    float v = local;
    int   c = (pos0 ? 1 : 0) + (pos1 ? 1 : 0);
    #pragma unroll
    for (int off = 32; off > 0; off >>= 1) {
        v += __shfl_down(v, off, 64);
        c += __shfl_down(c, off, 64);
    }
    __shared__ float s_sum[BLK / 64];
    __shared__ int   s_cnt[BLK / 64];
    const int wave = threadIdx.x >> 6;
    if ((threadIdx.x & 63) == 0) { s_sum[wave] = v; s_cnt[wave] = c; }
    __syncthreads();

    if (threadIdx.x == 0) {
        float t = 0.0f; int tc = 0;
        #pragma unroll
        for (int w = 0; w < BLK / 64; ++w) { t += s_sum[w]; tc += s_cnt[w]; }
        // pack: arrival | count | fixed-point sum  (all fields overflow-safe)
        const u64 pack = (1ull << 58) | ((u64)tc << 44)
                       | (u64)__float2ll_rn(t * SUM_SCALE);
        const u64 old = atomicAdd(&gpack[b], pack);
        if ((old >> 58) == (u64)(BLKS_PER_IMG - 1)) {
            // we are the last arriver: old + our pack == exact final total
            const u64 tot = old + pack;
            const u64 cnt = (tot >> 44) & 0x3FFFull;
            const float sum = (float)(tot & ((1ull << 44) - 1ull)) * (1.0f / SUM_SCALE);
            out[b]         = sum / fmaxf((float)cnt, 1.0f);  // cls_loss
            out[BATCH + b] = 0.0f;                           // reg_loss (no-op)
        }
    }
}

extern "C" void kernel_launch(void* const* d_in, const int* in_sizes, int n_in,
                              void* d_out, int out_size, void* d_ws, size_t ws_size,
                              hipStream_t stream) {
    const float* pred    = (const float*)d_in[0];   // (B, A, G, G, 85)
    const float* ann     = (const float*)d_in[1];   // (B, MAXB, 5)
    const float* anchors = (const float*)d_in[2];   // (A, G, G, 4)
    float* out = (float*)d_out;

    u64* gpack = (u64*)d_ws;
    // zero the 32 packed accumulators every call (graph-capturable node)
    (void)hipMemsetAsync(gpack, 0, sizeof(u64) * BATCH, stream);

    dim3 grid(BLKS_PER_IMG, BATCH);
    yolo_fused<<<grid, BLK, 0, stream>>>(pred, ann, anchors, gpack, out);
}

// Round 7
// 19.392 us; speedup vs baseline: 1.1337x; 1.1337x over previous
//
#include <hip/hip_runtime.h>

// Problem constants (match reference setup_inputs)
#define BATCH   32
#define NCLS    80
#define MAXB    50
#define NANCH   12288                   // 3*64*64 anchors per image
#define BLK     256
#define BLKS_PER_IMG 48                 // NANCH / BLK
#define ROWLEN  85                      // NCLS + 5

typedef unsigned long long u64;

// Kernel 1: per-anchor IoU matching + wave-cooperative BCE.
// - Valid annotations compacted order-preservingly (ballot/popcount); loop
//   runs over ~60% of MAXB. Loss-equivalent to reference's iou=-1 masking
//   (argmax only consumed when positive; empty list -> loss 0).
// - Division-free-ish IoU via v_rcp (union >= area_a >= 256; 1-ulp rcp only
//   perturbs measure-zero ties, threshold is 1.55).
// - BCE: instead of 80 exec-masked lane-divergent loads per wave, the wave
//   iterates its positive lanes (ballot+ffs) and loads each 80-class row
//   COALESCED (lane c -> prow[c], lanes 0..15 -> prow[64+c]); per-lane
//   partials feed the existing block reduction, no per-positive reduce.
__global__ __launch_bounds__(BLK) void yolo_match_bce(
    const float* __restrict__ pred,      // (B, NANCH, 85)
    const float* __restrict__ ann,       // (B, MAXB, 5)
    const float* __restrict__ anchors,   // (NANCH, 4)
    float* __restrict__ psum,            // (B, BLKS_PER_IMG)
    int*   __restrict__ pcnt)            // (B, BLKS_PER_IMG)
{
    const int blk  = blockIdx.x;                // 0..47
    const int b    = blockIdx.y;                // image
    const int n    = blk * BLK + threadIdx.x;   // anchor index
    const int lane = threadIdx.x & 63;

    __shared__ float4 s_box[MAXB];   // compacted corners x1,y1,x2,y2
    __shared__ float  s_area[MAXB];  // compacted box area
    __shared__ float  s_cls[MAXB];   // compacted class
    __shared__ int    s_nv;          // number of valid boxes

    // Wave-0 (lanes 0..49) compacts the annotation list (order-preserving).
    if (threadIdx.x < 64) {
        float cx = 0, cy = 0, w = 0, h = 0, cl = -1.0f;
        if (threadIdx.x < MAXB) {
            const float* a = ann + ((size_t)b * MAXB + threadIdx.x) * 5;
            cx = a[0]; cy = a[1]; w = a[2]; h = a[3]; cl = a[4];
        }
        const bool valid = (threadIdx.x < MAXB) && (cl != -1.0f);
        const u64 mask = __ballot(valid);
        if (valid) {
            const int cidx = __popcll(mask & ((1ull << threadIdx.x) - 1ull));
            const float x1 = cx - w * 0.5f, y1 = cy - h * 0.5f;
            const float x2 = cx + w * 0.5f, y2 = cy + h * 0.5f;
            s_box[cidx]  = make_float4(x1, y1, x2, y2);
            s_area[cidx] = (x2 - x1) * (y2 - y1);
            s_cls[cidx]  = cl;
        }
        if (threadIdx.x == 0) s_nv = __popcll(mask);
    }
    __syncthreads();

    const float4 a4 = *reinterpret_cast<const float4*>(anchors + (size_t)n * 4);
    const float ax1 = a4.x - a4.z * 0.5f, ay1 = a4.y - a4.w * 0.5f;
    const float ax2 = a4.x + a4.z * 0.5f, ay2 = a4.y + a4.w * 0.5f;
    const float area_a = (ax2 - ax1) * (ay2 - ay1);

    const int nv = s_nv;
    float best = 0.0f;     // best IoU so far (all IoUs >= 0)
    int   bestm = 0;
    #pragma unroll 5
    for (int m = 0; m < nv; ++m) {
        const float4 bb = s_box[m];                 // LDS broadcast reads
        float iw = fminf(ax2, bb.z) - fmaxf(ax1, bb.x); iw = fmaxf(iw, 0.0f);
        float ih = fminf(ay2, bb.w) - fmaxf(ay1, bb.y); ih = fmaxf(ih, 0.0f);
        const float inter = iw * ih;
        const float ua    = area_a + s_area[m] - inter;  // >= area_a >= 256
        const float iou   = inter * __builtin_amdgcn_rcpf(ua);
        // strict > keeps first occurrence, matching jnp.argmax
        if (iou > best) { best = iou; bestm = m; }
    }

    const bool positive = (best >= 0.5f);
    // per-lane assigned class (only meaningful when positive; when nv==0 the
    // value is junk but pmask==0 so it is never consumed)
    const int ac = (int)fminf(fmaxf(s_cls[bestm], 0.0f), (float)(NCLS - 1));

    // ---- wave-cooperative BCE over positive anchors ----
    // loss(anchor) = -log(pa) + log(1-pa) - sum_c log(1-p_c)
    float local = 0.0f;                       // per-lane partial across positives
    u64 pmask = __ballot(positive);
    const size_t waverow = (size_t)b * NANCH + (size_t)(n - lane);  // wave's first anchor row
    while (pmask) {
        const int src = __ffsll(pmask) - 1;
        pmask &= pmask - 1;
        const int pac = __shfl(ac, src);      // uniform src -> readlane
        const float* prow = pred + (waverow + (size_t)src) * ROWLEN + 5;
        const float p0 = prow[lane];                           // coalesced 256B
        const float p1 = (lane < 16) ? prow[64 + lane] : 0.0f; // coalesced 64B
        float t = __logf(1.0f - p0);          // p1=0 -> log(1)=0 contributes 0
        if (lane < 16) t += __logf(1.0f - p1);
        local -= t;                           // accumulates -sum_c log(1-p_c)
        const int   tl = (pac < 64) ? pac : (pac - 64);
        const float pv = (pac < 64) ? p0 : p1;
        if (lane == tl)
            local += -__logf(pv) + __logf(1.0f - pv);
    }

    // Deterministic block reduction: wave shuffle then cross-wave via LDS
    float v = local;
    int   c = positive ? 1 : 0;
    #pragma unroll
    for (int off = 32; off > 0; off >>= 1) {
        v += __shfl_down(v, off, 64);
        c += __shfl_down(c, off, 64);
    }
    __shared__ float s_sum[BLK / 64];
    __shared__ int   s_cnt[BLK / 64];
    const int wave = threadIdx.x >> 6;
    if ((threadIdx.x & 63) == 0) { s_sum[wave] = v; s_cnt[wave] = c; }
    __syncthreads();
    if (threadIdx.x == 0) {
        float t = 0.0f; int tc = 0;
        #pragma unroll
        for (int w = 0; w < BLK / 64; ++w) { t += s_sum[w]; tc += s_cnt[w]; }
        psum[b * BLKS_PER_IMG + blk] = t;
        pcnt[b * BLKS_PER_IMG + blk] = tc;
    }
}

// Kernel 2: reduce 48 partials per image -> final losses; write all outputs.
__global__ __launch_bounds__(64) void yolo_finalize(
    const float* __restrict__ psum,
    const int*   __restrict__ pcnt,
    float* __restrict__ out)             // (2, B): [cls_losses; reg_losses=0]
{
    const int b = blockIdx.x;
    const int t = threadIdx.x;           // 64 threads
    float v = (t < BLKS_PER_IMG) ? psum[b * BLKS_PER_IMG + t] : 0.0f;
    int   c = (t < BLKS_PER_IMG) ? pcnt[b * BLKS_PER_IMG + t] : 0;
    #pragma unroll
    for (int off = 32; off > 0; off >>= 1) {
        v += __shfl_down(v, off, 64);
        c += __shfl_down(c, off, 64);
    }
    if (t == 0) {
        const int np = (c > 1) ? c : 1;
        out[b]         = v / (float)np;  // cls_loss
        out[BATCH + b] = 0.0f;           // reg_loss (no-op branch in source)
    }
}

extern "C" void kernel_launch(void* const* d_in, const int* in_sizes, int n_in,
                              void* d_out, int out_size, void* d_ws, size_t ws_size,
                              hipStream_t stream) {
    const float* pred    = (const float*)d_in[0];   // (B, A, G, G, 85)
    const float* ann     = (const float*)d_in[1];   // (B, MAXB, 5)
    const float* anchors = (const float*)d_in[2];   // (A, G, G, 4)
    float* out = (float*)d_out;

    float* psum = (float*)d_ws;
    int*   pcnt = (int*)((char*)d_ws + sizeof(float) * BATCH * BLKS_PER_IMG);

    dim3 grid1(BLKS_PER_IMG, BATCH);
    yolo_match_bce<<<grid1, BLK, 0, stream>>>(pred, ann, anchors, psum, pcnt);
    yolo_finalize<<<BATCH, 64, 0, stream>>>(psum, pcnt, out);
}